// Round 7
// baseline (136.003 us; speedup 1.0000x reference)
//
#include <hip/hip_runtime.h>
#include <hip/hip_bf16.h>

typedef __attribute__((ext_vector_type(4))) float f32x4;
typedef __attribute__((ext_vector_type(8))) short bf16x8;
typedef unsigned short u16;
typedef unsigned int u32;

// ---------- helpers ----------

__device__ __forceinline__ u16 f2bf(float f) {
  union { float f; unsigned int u; } v;
  v.f = f;
  unsigned int r = (v.u + 0x7fffu + ((v.u >> 16) & 1u)) >> 16;
  return (u16)r;
}

// async global->LDS, 16 bytes/lane; LDS dest = wave-uniform base + lane*16
__device__ __forceinline__ void async16(const void* g, const void* l) {
  __builtin_amdgcn_global_load_lds(
      (const __attribute__((address_space(1))) unsigned int*)(unsigned long)g,
      (__attribute__((address_space(3))) unsigned int*)(unsigned int)(unsigned long)l,
      16, 0, 0);
}

__device__ __forceinline__ void bar() {
  asm volatile("" ::: "memory");
  __builtin_amdgcn_s_barrier();
  asm volatile("" ::: "memory");
}

#define WAIT_VM0() asm volatile("s_waitcnt vmcnt(0)" ::: "memory")

// ---------- 1) plain fp32 -> bf16 convert (Q) ----------

__global__ __launch_bounds__(256) void cvt_plain(const float* __restrict__ in,
                                                 u16* __restrict__ out, int n4) {
  int stride = gridDim.x * blockDim.x;
  for (int i = blockIdx.x * blockDim.x + threadIdx.x; i < n4; i += stride) {
    f32x4 v = *(const f32x4*)(in + (long)i * 4);
    ushort4 o;
    o.x = f2bf(v.x); o.y = f2bf(v.y); o.z = f2bf(v.z); o.w = f2bf(v.w);
    *(ushort4*)(out + (long)i * 4) = o;
  }
}

// ---------- 2) fused K+V transposed convert: fp32 [2048][1024] -> bf16 [1024][2048] ----------

__global__ __launch_bounds__(256) void cvt_kv(const float* __restrict__ Kin,
                                              const float* __restrict__ Vin,
                                              u16* __restrict__ Kt,
                                              u16* __restrict__ Vt) {
  __shared__ u16 tile[64][68];
  const int z = blockIdx.z;           // 0..15: batch = z>>1, tensor = z&1
  const int bsel = z >> 1;
  const float* in = (z & 1) ? Kin : Vin;
  u16* out = (z & 1) ? Kt : Vt;
  const long bo = (long)bsel * 2048 * 1024;
  const int r0 = blockIdx.y * 64;     // n
  const int c0 = blockIdx.x * 64;     // h/d
  const int t = threadIdx.x;
  const int tr = t >> 4;
  const int tc4 = (t & 15) * 4;

#pragma unroll
  for (int i = 0; i < 4; ++i) {
    int r = i * 16 + tr;
    f32x4 v = *(const f32x4*)(in + bo + (long)(r0 + r) * 1024 + c0 + tc4);
    tile[tc4 + 0][r] = f2bf(v.x);
    tile[tc4 + 1][r] = f2bf(v.y);
    tile[tc4 + 2][r] = f2bf(v.z);
    tile[tc4 + 3][r] = f2bf(v.w);
  }
  __syncthreads();
#pragma unroll
  for (int i = 0; i < 4; ++i) {
    int c = i * 16 + tr;
    ushort4 u = *(const ushort4*)(&tile[c][tc4]);
    *(ushort4*)(out + bo + (long)(c0 + c) * 2048 + r0 + tc4) = u;
  }
}

// ===================================================================
// NT GEMM template (the proven R6-gemmA structure, K parameterized):
// C[m][n] = sum_k A[m][k] * Bt[n][k], bf16 in, f32 acc.
// BM=256, BN=128, BK=64. 512 thr = 8 waves (2M x 4N), per-wave 128x32.
// Both operands staged via global_load_lds (pre-swizzled global source,
// linear LDS dest -> zero VALU staging cost, 0 bank conflicts).
// Single barrier per K-tile (drift schedule), vmcnt(0) at tile boundary.
// Grid: nTiles*8, batch = bid&7 (XCD pin), n-tile fastest for A-panel reuse.
// ===================================================================
template <bool BF16OUT>
__global__ __launch_bounds__(512, 2) void gemm_nt(const u16* __restrict__ A,
                                                  const u16* __restrict__ Bt,
                                                  void* __restrict__ Cv,
                                                  int K, int NT, int nTN,
                                                  long sA, long sB, long sC) {
  __shared__ u16 As[2][256][64];  // 64 KB
  __shared__ u16 Bs[2][128][64];  // 32 KB

  const int bid = blockIdx.x;
  const int b = bid & 7;              // batch -> XCD pin
  const int tile = bid >> 3;
  const int bn0 = (tile % nTN) * 128;
  const int bm0 = (tile / nTN) * 256;

  const int tid = threadIdx.x;
  const int lane = tid & 63;
  const int wave = tid >> 6;
  const int wr = wave >> 2;  // 0..1 (M)
  const int wc = wave & 3;   // 0..3 (N)
  const int l16 = lane & 15;
  const int kh = lane >> 4;

  const char* Ab = (const char*)(A + (long)b * sA);
  const char* Bb = (const char*)(Bt + (long)b * sB);

  // staging offsets (pre-swizzled global source, linear LDS dest)
  const int rowbytes = K * 2;
  int aoff[4], boff[2];
#pragma unroll
  for (int i = 0; i < 4; ++i) {
    int u = tid + i * 512;                       // 0..2047
    int row = u >> 3, sl = (u & 7) ^ (row & 7);
    aoff[i] = (bm0 + row) * rowbytes + sl * 16;
  }
#pragma unroll
  for (int i = 0; i < 2; ++i) {
    int u = tid + i * 512;                       // 0..1023
    int row = u >> 3, sl = (u & 7) ^ (row & 7);
    boff[i] = (bn0 + row) * rowbytes + sl * 16;
  }

#define STG_A(buf)                                                          \
  {                                                                         \
    _Pragma("unroll") for (int i_ = 0; i_ < 4; ++i_) {                      \
      async16(Ab + aoff[i_], (char*)&As[buf][0][0] + (tid + i_ * 512) * 16);\
      aoff[i_] += 128;                                                      \
    }                                                                       \
  }
#define STG_B(buf)                                                          \
  {                                                                         \
    _Pragma("unroll") for (int i_ = 0; i_ < 2; ++i_) {                      \
      async16(Bb + boff[i_], (char*)&Bs[buf][0][0] + (tid + i_ * 512) * 16);\
      boff[i_] += 128;                                                      \
    }                                                                       \
  }

  // fragment read offsets (elements); row&7 == l16&7 for all fragment rows
  int offA[2][4][2];  // [qm][f][ks]
#pragma unroll
  for (int q = 0; q < 2; ++q)
#pragma unroll
    for (int f = 0; f < 4; ++f) {
      int r = q * 128 + wr * 64 + f * 16 + l16;
#pragma unroll
      for (int ks = 0; ks < 2; ++ks)
        offA[q][f][ks] = r * 64 + (((ks * 4 + kh) ^ (l16 & 7)) * 8);
    }
  int offB[2][2];  // [fn][ks]
#pragma unroll
  for (int fn = 0; fn < 2; ++fn) {
    int r = fn * 64 + wc * 16 + l16;
#pragma unroll
    for (int ks = 0; ks < 2; ++ks)
      offB[fn][ks] = r * 64 + (((ks * 4 + kh) ^ (l16 & 7)) * 8);
  }

  f32x4 acc[8][2] = {};
  bf16x8 ar[4][2], br[2][2];

  // prologue: stage tile 0
  STG_A(0); STG_B(0);
  WAIT_VM0();
  bar();

  for (int t = 0; t < NT; ++t) {
    const int cur = t & 1, nxt = cur ^ 1;
    const bool g = (t + 1 < NT);
    const u16* Abuf = &As[cur][0][0];
    const u16* Bbuf = &Bs[cur][0][0];

    // reads: A half0 + all B
#pragma unroll
    for (int f = 0; f < 4; ++f)
#pragma unroll
      for (int ks = 0; ks < 2; ++ks)
        ar[f][ks] = *(const bf16x8*)(Abuf + offA[0][f][ks]);
#pragma unroll
    for (int fn = 0; fn < 2; ++fn)
#pragma unroll
      for (int ks = 0; ks < 2; ++ks)
        br[fn][ks] = *(const bf16x8*)(Bbuf + offB[fn][ks]);

    // issue next-tile staging
    if (g) { STG_A(nxt); STG_B(nxt); }

    // MMA half 0 (16 MFMA)
    __builtin_amdgcn_s_setprio(1);
#pragma unroll
    for (int f = 0; f < 4; ++f)
#pragma unroll
      for (int n = 0; n < 2; ++n)
#pragma unroll
        for (int ks = 0; ks < 2; ++ks)
          acc[f][n] = __builtin_amdgcn_mfma_f32_16x16x32_bf16(
              ar[f][ks], br[n][ks], acc[f][n], 0, 0, 0);
    __builtin_amdgcn_s_setprio(0);

    // reads: A half1
#pragma unroll
    for (int f = 0; f < 4; ++f)
#pragma unroll
      for (int ks = 0; ks < 2; ++ks)
        ar[f][ks] = *(const bf16x8*)(Abuf + offA[1][f][ks]);

    // MMA half 1
    __builtin_amdgcn_s_setprio(1);
#pragma unroll
    for (int f = 0; f < 4; ++f)
#pragma unroll
      for (int n = 0; n < 2; ++n)
#pragma unroll
        for (int ks = 0; ks < 2; ++ks)
          acc[4 + f][n] = __builtin_amdgcn_mfma_f32_16x16x32_bf16(
              ar[f][ks], br[n][ks], acc[4 + f][n], 0, 0, 0);
    __builtin_amdgcn_s_setprio(0);

    if (g) WAIT_VM0();  // staged tile resident before next iteration's reads
    bar();
  }
#undef STG_A
#undef STG_B

  // epilogue: C/D col = l16, row = kh*4 + r; output pitch 1024
  u16*   Cb = (u16*)Cv + (long)b * sC;
  float* Cf = (float*)Cv + (long)b * sC;
#pragma unroll
  for (int fm = 0; fm < 8; ++fm) {
    const int gm = bm0 + (fm >> 2) * 128 + wr * 64 + (fm & 3) * 16 + kh * 4;
#pragma unroll
    for (int fn = 0; fn < 2; ++fn) {
      const int gn = bn0 + fn * 64 + wc * 16 + l16;
#pragma unroll
      for (int r = 0; r < 4; ++r) {
        if (BF16OUT) Cb[(long)(gm + r) * 1024 + gn] = f2bf(acc[fm][fn][r]);
        else         Cf[(long)(gm + r) * 1024 + gn] = acc[fm][fn][r];
      }
    }
  }
}

// ---------- launch ----------

extern "C" void kernel_launch(void* const* d_in, const int* in_sizes, int n_in,
                              void* d_out, int out_size, void* d_ws, size_t ws_size,
                              hipStream_t stream) {
  const float* Q  = (const float*)d_in[0];
  const float* Kf = (const float*)d_in[1];
  // d_in[2] = span   (unused by the reference's returned value)
  const float* V  = (const float*)d_in[3];
  // d_in[4] = key_pe (unused)
  float* out = (float*)d_out;

  // workspace: Vt 32MB, Kt 32MB, Pt 16MB, Qb 32MB  (112 MB)
  char* ws = (char*)d_ws;
  u16* Vt = (u16*)(ws);
  u16* Kt = (u16*)(ws + (size_t)32 * 1024 * 1024);
  u16* Pt = (u16*)(ws + (size_t)64 * 1024 * 1024);
  u16* Qb = (u16*)(ws + (size_t)80 * 1024 * 1024);

  // 1) converts
  cvt_kv<<<dim3(16, 32, 16), 256, 0, stream>>>(Kf, V, Kt, Vt);
  cvt_plain<<<4096, 256, 0, stream>>>(Q, Qb, 8 * 2048 * 1024 / 4);

  // 2) GEMM A: Pt[d][h] = sum_n Vt[d][n]*Kt[h][n]
  //    per batch M=1024,N=1024,K=2048 -> 4x8=32 tiles, 256 blocks
  gemm_nt<true><<<256, 512, 0, stream>>>(
      Vt, Kt, (void*)Pt, 2048, 32, 8,
      (long)1024 * 2048, (long)1024 * 2048, (long)1024 * 1024);

  // 3) GEMM B: out[m][d] = sum_h Qb[m][h]*Pt[d][h]
  //    per batch M=2048,N=1024,K=1024 -> 8x8=64 tiles, 512 blocks
  gemm_nt<false><<<512, 512, 0, stream>>>(
      Qb, Pt, (void*)out, 1024, 16, 8,
      (long)2048 * 1024, (long)1024 * 1024, (long)2048 * 1024);
}

// Round 8
// 135.381 us; speedup vs baseline: 1.0046x; 1.0046x over previous
//
#include <hip/hip_runtime.h>
#include <hip/hip_bf16.h>

typedef __attribute__((ext_vector_type(4))) float f32x4;
typedef __attribute__((ext_vector_type(8))) short bf16x8;
typedef __attribute__((ext_vector_type(8))) unsigned short u16x8;
typedef __attribute__((ext_vector_type(2))) unsigned int u32x2;
typedef unsigned short u16;
typedef unsigned int u32;

// ---------- helpers ----------

__device__ __forceinline__ u16 f2bf(float f) {
  union { float f; unsigned int u; } v;
  v.f = f;
  unsigned int r = (v.u + 0x7fffu + ((v.u >> 16) & 1u)) >> 16;
  return (u16)r;
}

// packed f32->bf16 (RNE): u32 = [bf(a) | bf(b)<<16]  (a at lower address)
__device__ __forceinline__ u32 pk2(float a, float b) {
  u32 r;
  asm("v_cvt_pk_bf16_f32 %0, %1, %2" : "=v"(r) : "v"(a), "v"(b));
  return r;
}

// async global->LDS, 16 bytes/lane; LDS dest = wave-uniform base + lane*16
__device__ __forceinline__ void async16(const void* g, const void* l) {
  __builtin_amdgcn_global_load_lds(
      (const __attribute__((address_space(1))) unsigned int*)(unsigned long)g,
      (__attribute__((address_space(3))) unsigned int*)(unsigned int)(unsigned long)l,
      16, 0, 0);
}

__device__ __forceinline__ void bar() {
  asm volatile("" ::: "memory");
  __builtin_amdgcn_s_barrier();
  asm volatile("" ::: "memory");
}

#define WAIT_VM0() asm volatile("s_waitcnt vmcnt(0)" ::: "memory")

// ---------- 1) plain fp32 -> bf16 convert (Q) ----------

__global__ __launch_bounds__(256) void cvt_plain(const float* __restrict__ in,
                                                 u16* __restrict__ out, int n4) {
  int stride = gridDim.x * blockDim.x;
  for (int i = blockIdx.x * blockDim.x + threadIdx.x; i < n4; i += stride) {
    f32x4 v = *(const f32x4*)(in + (long)i * 4);
    ushort4 o;
    o.x = f2bf(v.x); o.y = f2bf(v.y); o.z = f2bf(v.z); o.w = f2bf(v.w);
    *(ushort4*)(out + (long)i * 4) = o;
  }
}

// ---------- 2) fused K+V transposed convert: fp32 [2048][1024] -> bf16 [1024][2048] ----------
// Tile 128(n) x 64(c) per block. Register 4x4 quad-transpose -> ds_write_b64;
// LDS XOR-swizzled at 16B-group granularity (group' = group ^ (c&15)) ->
// conflict-free b128 reads; 16B global stores (256B/16-lane segments).

__global__ __launch_bounds__(256) void cvt_kv(const float* __restrict__ Kin,
                                              const float* __restrict__ Vin,
                                              u16* __restrict__ Kt,
                                              u16* __restrict__ Vt) {
  __shared__ char tile[16384];  // logical [c=64][n=128] bf16, swizzled

  const int z = blockIdx.z;            // 0..15: batch = z>>1, tensor = z&1
  const int bsel = z >> 1;
  const float* in = (z & 1) ? Kin : Vin;
  u16* out = (z & 1) ? Kt : Vt;
  const long bo = (long)bsel * 2048 * 1024;
  const int r0 = blockIdx.y * 128;     // n base
  const int c0 = blockIdx.x * 64;      // c base (h/d)

  const int t = threadIdx.x;
  const int c4 = (t & 15) * 4;         // c sub-base, 0..60
  const int n4b = (t >> 4) * 4;        // n sub-base, 0..60

  // ---- load 4 rows x 4 cols per half, transpose in registers ----
  f32x4 v[2][4];
#pragma unroll
  for (int i = 0; i < 2; ++i)
#pragma unroll
    for (int r = 0; r < 3 + 1; ++r)
      v[i][r] = *(const f32x4*)(in + bo + (long)(r0 + i * 64 + n4b + r) * 1024 +
                                c0 + c4);

#pragma unroll
  for (int i = 0; i < 2; ++i) {
    const int n4 = i * 64 + n4b;       // 0..124, multiple of 4
    const int grp = n4 >> 3;           // 16B group index 0..15
    const int sub = (n4 & 4) * 2;      // byte offset within group: 0 or 8
#pragma unroll
    for (int q = 0; q < 4; ++q) {
      const int c = c4 + q;
      u32x2 w;
      w.x = pk2(v[i][0][q], v[i][1][q]);   // rows n4+0, n4+1
      w.y = pk2(v[i][2][q], v[i][3][q]);   // rows n4+2, n4+3
      *(u32x2*)(tile + c * 256 + ((grp ^ (c & 15)) << 4) + sub) = w;
    }
  }
  __syncthreads();

  // ---- read b128 + 16B global store ----
  const int g = t & 15;                // n-group handled by this lane
#pragma unroll
  for (int p = 0; p < 4; ++p) {
    const int c = (t >> 4) + p * 16;   // 0..63
    u16x8 u = *(const u16x8*)(tile + c * 256 + ((g ^ (c & 15)) << 4));
    *(u16x8*)(out + bo + (long)(c0 + c) * 2048 + r0 + g * 8) = u;
  }
}

// ===================================================================
// NT GEMM template (proven R6-gemmA structure, K parameterized):
// C[m][n] = sum_k A[m][k] * Bt[n][k], bf16 in, f32 acc.
// BM=256, BN=128, BK=64. 512 thr = 8 waves (2M x 4N), per-wave 128x32.
// Both operands staged via global_load_lds (pre-swizzled global source,
// linear LDS dest). Single barrier per K-tile (drift schedule).
// Grid: nTiles*8, batch = bid&7 (XCD pin), n-tile fastest.
// ===================================================================
template <bool BF16OUT>
__global__ __launch_bounds__(512, 2) void gemm_nt(const u16* __restrict__ A,
                                                  const u16* __restrict__ Bt,
                                                  void* __restrict__ Cv,
                                                  int K, int NT, int nTN,
                                                  long sA, long sB, long sC) {
  __shared__ u16 As[2][256][64];  // 64 KB
  __shared__ u16 Bs[2][128][64];  // 32 KB

  const int bid = blockIdx.x;
  const int b = bid & 7;              // batch -> XCD pin
  const int tile = bid >> 3;
  const int bn0 = (tile % nTN) * 128;
  const int bm0 = (tile / nTN) * 256;

  const int tid = threadIdx.x;
  const int lane = tid & 63;
  const int wave = tid >> 6;
  const int wr = wave >> 2;  // 0..1 (M)
  const int wc = wave & 3;   // 0..3 (N)
  const int l16 = lane & 15;
  const int kh = lane >> 4;

  const char* Ab = (const char*)(A + (long)b * sA);
  const char* Bb = (const char*)(Bt + (long)b * sB);

  const int rowbytes = K * 2;
  int aoff[4], boff[2];
#pragma unroll
  for (int i = 0; i < 4; ++i) {
    int u = tid + i * 512;
    int row = u >> 3, sl = (u & 7) ^ (row & 7);
    aoff[i] = (bm0 + row) * rowbytes + sl * 16;
  }
#pragma unroll
  for (int i = 0; i < 2; ++i) {
    int u = tid + i * 512;
    int row = u >> 3, sl = (u & 7) ^ (row & 7);
    boff[i] = (bn0 + row) * rowbytes + sl * 16;
  }

#define STG_A(buf)                                                          \
  {                                                                         \
    _Pragma("unroll") for (int i_ = 0; i_ < 4; ++i_) {                      \
      async16(Ab + aoff[i_], (char*)&As[buf][0][0] + (tid + i_ * 512) * 16);\
      aoff[i_] += 128;                                                      \
    }                                                                       \
  }
#define STG_B(buf)                                                          \
  {                                                                         \
    _Pragma("unroll") for (int i_ = 0; i_ < 2; ++i_) {                      \
      async16(Bb + boff[i_], (char*)&Bs[buf][0][0] + (tid + i_ * 512) * 16);\
      boff[i_] += 128;                                                      \
    }                                                                       \
  }

  int offA[2][4][2];  // [qm][f][ks]
#pragma unroll
  for (int q = 0; q < 2; ++q)
#pragma unroll
    for (int f = 0; f < 4; ++f) {
      int r = q * 128 + wr * 64 + f * 16 + l16;
#pragma unroll
      for (int ks = 0; ks < 2; ++ks)
        offA[q][f][ks] = r * 64 + (((ks * 4 + kh) ^ (l16 & 7)) * 8);
    }
  int offB[2][2];  // [fn][ks]
#pragma unroll
  for (int fn = 0; fn < 2; ++fn) {
    int r = fn * 64 + wc * 16 + l16;
#pragma unroll
    for (int ks = 0; ks < 2; ++ks)
      offB[fn][ks] = r * 64 + (((ks * 4 + kh) ^ (l16 & 7)) * 8);
  }

  f32x4 acc[8][2] = {};
  bf16x8 ar[4][2], br[2][2];

  STG_A(0); STG_B(0);
  WAIT_VM0();
  bar();

  for (int t = 0; t < NT; ++t) {
    const int cur = t & 1, nxt = cur ^ 1;
    const bool g = (t + 1 < NT);
    const u16* Abuf = &As[cur][0][0];
    const u16* Bbuf = &Bs[cur][0][0];

#pragma unroll
    for (int f = 0; f < 4; ++f)
#pragma unroll
      for (int ks = 0; ks < 2; ++ks)
        ar[f][ks] = *(const bf16x8*)(Abuf + offA[0][f][ks]);
#pragma unroll
    for (int fn = 0; fn < 2; ++fn)
#pragma unroll
      for (int ks = 0; ks < 2; ++ks)
        br[fn][ks] = *(const bf16x8*)(Bbuf + offB[fn][ks]);

    if (g) { STG_A(nxt); STG_B(nxt); }

    __builtin_amdgcn_s_setprio(1);
#pragma unroll
    for (int f = 0; f < 4; ++f)
#pragma unroll
      for (int n = 0; n < 2; ++n)
#pragma unroll
        for (int ks = 0; ks < 2; ++ks)
          acc[f][n] = __builtin_amdgcn_mfma_f32_16x16x32_bf16(
              ar[f][ks], br[n][ks], acc[f][n], 0, 0, 0);
    __builtin_amdgcn_s_setprio(0);

#pragma unroll
    for (int f = 0; f < 4; ++f)
#pragma unroll
      for (int ks = 0; ks < 2; ++ks)
        ar[f][ks] = *(const bf16x8*)(Abuf + offA[1][f][ks]);

    __builtin_amdgcn_s_setprio(1);
#pragma unroll
    for (int f = 0; f < 4; ++f)
#pragma unroll
      for (int n = 0; n < 2; ++n)
#pragma unroll
        for (int ks = 0; ks < 2; ++ks)
          acc[4 + f][n] = __builtin_amdgcn_mfma_f32_16x16x32_bf16(
              ar[f][ks], br[n][ks], acc[4 + f][n], 0, 0, 0);
    __builtin_amdgcn_s_setprio(0);

    if (g) WAIT_VM0();
    bar();
  }
#undef STG_A
#undef STG_B

  u16*   Cb = (u16*)Cv + (long)b * sC;
  float* Cf = (float*)Cv + (long)b * sC;
#pragma unroll
  for (int fm = 0; fm < 8; ++fm) {
    const int gm = bm0 + (fm >> 2) * 128 + wr * 64 + (fm & 3) * 16 + kh * 4;
#pragma unroll
    for (int fn = 0; fn < 2; ++fn) {
      const int gn = bn0 + fn * 64 + wc * 16 + l16;
#pragma unroll
      for (int r = 0; r < 4; ++r) {
        if (BF16OUT) Cb[(long)(gm + r) * 1024 + gn] = f2bf(acc[fm][fn][r]);
        else         Cf[(long)(gm + r) * 1024 + gn] = acc[fm][fn][r];
      }
    }
  }
}

// ---------- launch ----------

extern "C" void kernel_launch(void* const* d_in, const int* in_sizes, int n_in,
                              void* d_out, int out_size, void* d_ws, size_t ws_size,
                              hipStream_t stream) {
  const float* Q  = (const float*)d_in[0];
  const float* Kf = (const float*)d_in[1];
  // d_in[2] = span   (unused by the reference's returned value)
  const float* V  = (const float*)d_in[3];
  // d_in[4] = key_pe (unused)
  float* out = (float*)d_out;

  // workspace: Vt 32MB, Kt 32MB, Pt 16MB, Qb 32MB  (112 MB)
  char* ws = (char*)d_ws;
  u16* Vt = (u16*)(ws);
  u16* Kt = (u16*)(ws + (size_t)32 * 1024 * 1024);
  u16* Pt = (u16*)(ws + (size_t)64 * 1024 * 1024);
  u16* Qb = (u16*)(ws + (size_t)80 * 1024 * 1024);

  // 1) converts
  cvt_kv<<<dim3(16, 16, 16), 256, 0, stream>>>(Kf, V, Kt, Vt);
  cvt_plain<<<4096, 256, 0, stream>>>(Q, Qb, 8 * 2048 * 1024 / 4);

  // 2) GEMM A: Pt[d][h] = sum_n Vt[d][n]*Kt[h][n]
  //    per batch M=1024,N=1024,K=2048 -> 4x8=32 tiles, 256 blocks
  gemm_nt<true><<<256, 512, 0, stream>>>(
      Vt, Kt, (void*)Pt, 2048, 32, 8,
      (long)1024 * 2048, (long)1024 * 2048, (long)1024 * 1024);

  // 3) GEMM B: out[m][d] = sum_h Qb[m][h]*Pt[d][h]
  //    per batch M=2048,N=1024,K=1024 -> 8x8=64 tiles, 512 blocks
  gemm_nt<false><<<512, 512, 0, stream>>>(
      Qb, Pt, (void*)out, 1024, 16, 8,
      (long)2048 * 1024, (long)1024 * 1024, (long)2048 * 1024);
}